// Round 4
// baseline (458.611 us; speedup 1.0000x reference)
//
#include <hip/hip_runtime.h>
#include <cstdint>
#include <cstddef>

#define N_NODES 50000
#define N_EDGES 800000
#define D 512
#define M_PAD 50048   // 391 * 128

typedef __bf16 bf16x8 __attribute__((ext_vector_type(8)));
typedef float floatx4 __attribute__((ext_vector_type(4)));

typedef const __attribute__((address_space(1))) unsigned int* gas_u32p;
typedef __attribute__((address_space(3))) unsigned int* las_u32p;

__device__ __forceinline__ unsigned short f2bf(float f) {
    unsigned int u = __builtin_bit_cast(unsigned int, f);
    u += 0x7FFFu + ((u >> 16) & 1u);
    return (unsigned short)(u >> 16);
}
__device__ __forceinline__ float bflo(unsigned int u) {
    return __builtin_bit_cast(float, u << 16);
}
__device__ __forceinline__ float bfhi(unsigned int u) {
    return __builtin_bit_cast(float, u & 0xFFFF0000u);
}

// ---- u_f (f32, 50000x512) -> u_bf16 (padded to 50048 rows, zeros) ----
__global__ __launch_bounds__(256) void k_convert_u(const float* __restrict__ u,
                                                   unsigned short* __restrict__ ub) {
    size_t i = (size_t)blockIdx.x * 256 + threadIdx.x;   // 8 elems per thread
    size_t base = i * 8;
    if (base >= (size_t)M_PAD * D) return;
    uint4 o;
    if (base < (size_t)N_NODES * D) {
        const float4* s = (const float4*)(u + base);
        float4 a = s[0], b = s[1];
        o.x = (unsigned)f2bf(a.x) | ((unsigned)f2bf(a.y) << 16);
        o.y = (unsigned)f2bf(a.z) | ((unsigned)f2bf(a.w) << 16);
        o.z = (unsigned)f2bf(b.x) | ((unsigned)f2bf(b.y) << 16);
        o.w = (unsigned)f2bf(b.z) | ((unsigned)f2bf(b.w) << 16);
    } else {
        o = make_uint4(0u, 0u, 0u, 0u);
    }
    *(uint4*)(ub + base) = o;
}

// ---- weight (f32, 512x512 row-major [k][n]) -> WT bf16 [n][k] ----
__global__ __launch_bounds__(256) void k_convert_wt(const float* __restrict__ w,
                                                    unsigned short* __restrict__ wt) {
    int id = blockIdx.x * 256 + threadIdx.x;   // 262144 total, exact
    int n = id >> 9, k = id & 511;
    wt[id] = f2bf(w[k * D + n]);
}

// ---- row_ptr[i] = lower_bound(adj_rows, i), i in [0, N_NODES] ----
__global__ __launch_bounds__(256) void k_rowptr(const int* __restrict__ rows,
                                                int* __restrict__ rp) {
    int i = blockIdx.x * 256 + threadIdx.x;
    if (i > N_NODES) return;
    int lo = 0, hi = N_EDGES;
    while (lo < hi) {
        int mid = (lo + hi) >> 1;
        if (rows[mid] < i) lo = mid + 1; else hi = mid;
    }
    rp[i] = lo;
}

// ---- H = A(bf16, M_PAD x 512) @ W (via WT bf16 [n][k]) -> Hc chunk-major
// Hc[chunk][row(M_PAD)][32], chunk = n>>5.
__global__ __launch_bounds__(256) void k_gemm(const unsigned short* __restrict__ A,
                                              const unsigned short* __restrict__ WT,
                                              unsigned short* __restrict__ H) {
    __shared__ unsigned short lA[128 * 32];
    __shared__ unsigned short lB[128 * 32];
    const int tid  = threadIdx.x;
    const int wave = tid >> 6, lane = tid & 63;
    const int tileM0 = blockIdx.y * 128;
    const int tileN0 = blockIdx.x * 128;
    const int wr = wave >> 1, wc = wave & 1;

    const int lrow = lane >> 2, lslot = lane & 3;
    const int r0 = wave * 32;
    const int m0 = r0 + lrow,      m1 = r0 + 16 + lrow;
    const int q0 = (lslot - (m0 >> 1)) & 3;
    const int q1 = (lslot - (m1 >> 1)) & 3;
    const unsigned short* gA0 = A  + (size_t)(tileM0 + m0) * D + q0 * 8;
    const unsigned short* gA1 = A  + (size_t)(tileM0 + m1) * D + q1 * 8;
    const unsigned short* gB0 = WT + (size_t)(tileN0 + m0) * D + q0 * 8;
    const unsigned short* gB1 = WT + (size_t)(tileN0 + m1) * D + q1 * 8;
    unsigned short* lA0 = lA + r0 * 32;
    unsigned short* lA1 = lA + (r0 + 16) * 32;
    unsigned short* lB0 = lB + r0 * 32;
    unsigned short* lB1 = lB + (r0 + 16) * 32;

    floatx4 acc[4][4] = {};

    const int quad = lane >> 4, half = lane & 15;
    int offA[4], offB[4];
#pragma unroll
    for (int i = 0; i < 4; i++) {
        int m = wr * 64 + i * 16 + half;
        offA[i] = m * 32 + ((quad + (m >> 1)) & 3) * 8;
        int n = wc * 64 + i * 16 + half;
        offB[i] = n * 32 + ((quad + (n >> 1)) & 3) * 8;
    }

    for (int k0 = 0; k0 < D; k0 += 32) {
        __syncthreads();
        __builtin_amdgcn_global_load_lds((gas_u32p)(gA0 + k0), (las_u32p)lA0, 16, 0, 0);
        __builtin_amdgcn_global_load_lds((gas_u32p)(gA1 + k0), (las_u32p)lA1, 16, 0, 0);
        __builtin_amdgcn_global_load_lds((gas_u32p)(gB0 + k0), (las_u32p)lB0, 16, 0, 0);
        __builtin_amdgcn_global_load_lds((gas_u32p)(gB1 + k0), (las_u32p)lB1, 16, 0, 0);
        __syncthreads();

        bf16x8 af[4], bfr[4];
#pragma unroll
        for (int i = 0; i < 4; i++) {
            af[i]  = *(const bf16x8*)(lA + offA[i]);
            bfr[i] = *(const bf16x8*)(lB + offB[i]);
        }
#pragma unroll
        for (int i = 0; i < 4; i++)
#pragma unroll
            for (int j = 0; j < 4; j++)
                acc[i][j] = __builtin_amdgcn_mfma_f32_16x16x32_bf16(af[i], bfr[j], acc[i][j], 0, 0, 0);
    }

    // epilogue: C/D layout col = lane&15, row = quad*4 + r; chunk-major store
#pragma unroll
    for (int i = 0; i < 4; i++) {
        int gm0 = tileM0 + wr * 64 + i * 16 + quad * 4;
#pragma unroll
        for (int j = 0; j < 4; j++) {
            int gn = tileN0 + wc * 64 + j * 16 + half;
            int chunk = gn >> 5, nl = gn & 31;
#pragma unroll
            for (int r = 0; r < 4; r++) {
                H[((size_t)chunk * M_PAD + (gm0 + r)) * 32 + nl] = f2bf(acc[i][j][r]);
            }
        }
    }
}

// ---- out[row][c*32..] = relu( sum_e vals[e] * Hc[c][cols[e]][:] )
// One wave per (node, chunk); chunk c pinned to XCD c&7 via blockIdx%8
// (per-XCD L2 working set = 2 chunks x 3.2MB). Lean body: 16 edges in
// flight (2 groups of 8 edge-slots x 8 dim-lanes), clamp-to-last instead
// of predicated loads, 32-bit gather offsets.
__global__ __launch_bounds__(256) void k_scatter(const int* __restrict__ rp,
                                                 const int* __restrict__ cols,
                                                 const float* __restrict__ vals,
                                                 const unsigned short* __restrict__ Hc,
                                                 float* __restrict__ out) {
    const int b  = blockIdx.x;            // 200000 blocks = 8 xcd * 25000
    const int s8 = b & 7;
    const int t0 = b >> 3;                // [0, 25000)
    const int hi = (t0 >= 12500) ? 1 : 0;
    const int chunk = s8 + (hi << 3);     // XCD s8 handles chunks s8, s8+8
    const int grp = t0 - hi * 12500;
    const int wave = threadIdx.x >> 6, lane = threadIdx.x & 63;
    const int node = grp * 4 + wave;      // 12500*4 = 50000 exact
    const int eh = lane >> 3;             // edge slot (8)
    const int el = lane & 7;              // uint2 slot within 64B chunk row
    const int s  = rp[node];
    const int e1 = rp[node + 1] - 1;      // inclusive end; empty if e1 < s
    const char* Hb = (const char*)(Hc + (size_t)chunk * (M_PAD * 32));
    const unsigned co = (unsigned)el * 8u;
    float a0 = 0.f, a1 = 0.f, a2 = 0.f, a3 = 0.f;
    for (int t = s; t <= e1; t += 16) {
        int ti0 = t + eh, ti1 = ti0 + 8;
        int tc0 = ti0 < e1 ? ti0 : e1;
        int tc1 = ti1 < e1 ? ti1 : e1;
        int c0 = cols[tc0];
        int c1 = cols[tc1];
        float v0 = vals[tc0];
        float v1 = vals[tc1];
        v0 = (ti0 <= e1) ? v0 : 0.f;
        v1 = (ti1 <= e1) ? v1 : 0.f;
        uint2 d0 = *(const uint2*)(Hb + ((((unsigned)c0) << 6) | co));
        uint2 d1 = *(const uint2*)(Hb + ((((unsigned)c1) << 6) | co));
        a0 = fmaf(v0, bflo(d0.x), a0); a1 = fmaf(v0, bfhi(d0.x), a1);
        a2 = fmaf(v0, bflo(d0.y), a2); a3 = fmaf(v0, bfhi(d0.y), a3);
        a0 = fmaf(v1, bflo(d1.x), a0); a1 = fmaf(v1, bfhi(d1.x), a1);
        a2 = fmaf(v1, bflo(d1.y), a2); a3 = fmaf(v1, bfhi(d1.y), a3);
    }
    a0 += __shfl_xor(a0, 8);  a1 += __shfl_xor(a1, 8);
    a2 += __shfl_xor(a2, 8);  a3 += __shfl_xor(a3, 8);
    a0 += __shfl_xor(a0, 16); a1 += __shfl_xor(a1, 16);
    a2 += __shfl_xor(a2, 16); a3 += __shfl_xor(a3, 16);
    a0 += __shfl_xor(a0, 32); a1 += __shfl_xor(a1, 32);
    a2 += __shfl_xor(a2, 32); a3 += __shfl_xor(a3, 32);
    if (lane < 8) {
        *(float4*)(out + (size_t)node * D + chunk * 32 + el * 4) =
            make_float4(fmaxf(a0, 0.f), fmaxf(a1, 0.f),
                        fmaxf(a2, 0.f), fmaxf(a3, 0.f));
    }
}

extern "C" void kernel_launch(void* const* d_in, const int* in_sizes, int n_in,
                              void* d_out, int out_size, void* d_ws, size_t ws_size,
                              hipStream_t stream) {
    const int*   adj_rows = (const int*)d_in[0];
    const int*   adj_cols = (const int*)d_in[1];
    const float* adj_vals = (const float*)d_in[2];
    const float* u_f      = (const float*)d_in[3];
    const float* weight   = (const float*)d_in[4];
    float* out = (float*)d_out;

    char* ws = (char*)d_ws;
    unsigned short* wt_bf = (unsigned short*)ws;                       // 524,288 B
    unsigned short* h_bf  = (unsigned short*)(ws + 524288);            // 51,249,152 B
    int* rowptr           = (int*)(ws + 524288 + 51249152);            // 200,004 B

    // park bf16 copy of U in d_out (consumed by GEMM before scatter overwrites)
    unsigned short* u_bf = (unsigned short*)d_out;

    hipLaunchKernelGGL(k_convert_u,  dim3(12512), dim3(256), 0, stream, u_f, u_bf);
    hipLaunchKernelGGL(k_convert_wt, dim3(1024),  dim3(256), 0, stream, weight, wt_bf);
    hipLaunchKernelGGL(k_rowptr,     dim3(196),   dim3(256), 0, stream, adj_rows, rowptr);
    hipLaunchKernelGGL(k_gemm,       dim3(4, 391), dim3(256), 0, stream, u_bf, wt_bf, h_bf);
    hipLaunchKernelGGL(k_scatter,    dim3(200000), dim3(256), 0, stream, rowptr, adj_cols, adj_vals, h_bf, out);
}

// Round 5
// 355.073 us; speedup vs baseline: 1.2916x; 1.2916x over previous
//
#include <hip/hip_runtime.h>
#include <cstdint>
#include <cstddef>

#define N_NODES 50000
#define N_EDGES 800000
#define D 512
#define M_PAD 50048   // 391 * 128

typedef __bf16 bf16x8 __attribute__((ext_vector_type(8)));
typedef float floatx4 __attribute__((ext_vector_type(4)));

typedef const __attribute__((address_space(1))) unsigned int* gas_u32p;
typedef __attribute__((address_space(3))) unsigned int* las_u32p;

__device__ __forceinline__ unsigned short f2bf(float f) {
    unsigned int u = __builtin_bit_cast(unsigned int, f);
    u += 0x7FFFu + ((u >> 16) & 1u);
    return (unsigned short)(u >> 16);
}
__device__ __forceinline__ float bflo(unsigned int u) {
    return __builtin_bit_cast(float, u << 16);
}
__device__ __forceinline__ float bfhi(unsigned int u) {
    return __builtin_bit_cast(float, u & 0xFFFF0000u);
}

// ---- u_f (f32, 50000x512) -> u_bf16 (padded to 50048 rows, zeros) ----
__global__ __launch_bounds__(256) void k_convert_u(const float* __restrict__ u,
                                                   unsigned short* __restrict__ ub) {
    size_t i = (size_t)blockIdx.x * 256 + threadIdx.x;   // 8 elems per thread
    size_t base = i * 8;
    if (base >= (size_t)M_PAD * D) return;
    uint4 o;
    if (base < (size_t)N_NODES * D) {
        const float4* s = (const float4*)(u + base);
        float4 a = s[0], b = s[1];
        o.x = (unsigned)f2bf(a.x) | ((unsigned)f2bf(a.y) << 16);
        o.y = (unsigned)f2bf(a.z) | ((unsigned)f2bf(a.w) << 16);
        o.z = (unsigned)f2bf(b.x) | ((unsigned)f2bf(b.y) << 16);
        o.w = (unsigned)f2bf(b.z) | ((unsigned)f2bf(b.w) << 16);
    } else {
        o = make_uint4(0u, 0u, 0u, 0u);
    }
    *(uint4*)(ub + base) = o;
}

// ---- weight (f32, 512x512 row-major [k][n]) -> WT bf16 [n][k] ----
__global__ __launch_bounds__(256) void k_convert_wt(const float* __restrict__ w,
                                                    unsigned short* __restrict__ wt) {
    int id = blockIdx.x * 256 + threadIdx.x;   // 262144 total, exact
    int n = id >> 9, k = id & 511;
    wt[id] = f2bf(w[k * D + n]);
}

// ---- row_ptr[i] = lower_bound(adj_rows, i), i in [0, N_NODES] ----
__global__ __launch_bounds__(256) void k_rowptr(const int* __restrict__ rows,
                                                int* __restrict__ rp) {
    int i = blockIdx.x * 256 + threadIdx.x;
    if (i > N_NODES) return;
    int lo = 0, hi = N_EDGES;
    while (lo < hi) {
        int mid = (lo + hi) >> 1;
        if (rows[mid] < i) lo = mid + 1; else hi = mid;
    }
    rp[i] = lo;
}

// ---- H = A(bf16, M_PAD x 512) @ W (via WT bf16 [n][k]) -> bf16 [M_PAD x 512]
// 1D grid, XCD-aware swizzle: the 4 N-tiles of one M-row sit 8 blocks apart
// so round-robin dispatch puts them on the SAME XCD -> A-tile L2 reuse 4x.
__global__ __launch_bounds__(256) void k_gemm(const unsigned short* __restrict__ A,
                                              const unsigned short* __restrict__ WT,
                                              unsigned short* __restrict__ H) {
    __shared__ unsigned short lA[128 * 32];
    __shared__ unsigned short lB[128 * 32];
    int b = blockIdx.x;                 // 1564 = 391 * 4
    int mt, nt;
    if (b < 1536) {                     // 48 groups of (8 m-tiles x 4 n-tiles)
        mt = (b >> 5) * 8 + (b & 7);
        nt = (b >> 3) & 3;
    } else {                            // tail: 7 m-tiles x 4 n-tiles
        int r = b - 1536;
        mt = 384 + (r % 7);
        nt = r / 7;
    }
    const int tid  = threadIdx.x;
    const int wave = tid >> 6, lane = tid & 63;
    const int tileM0 = mt * 128;
    const int tileN0 = nt * 128;
    const int wr = wave >> 1, wc = wave & 1;

    const int lrow = lane >> 2, lslot = lane & 3;
    const int r0 = wave * 32;
    const int m0 = r0 + lrow,      m1 = r0 + 16 + lrow;
    const int q0 = (lslot - (m0 >> 1)) & 3;
    const int q1 = (lslot - (m1 >> 1)) & 3;
    const unsigned short* gA0 = A  + (size_t)(tileM0 + m0) * D + q0 * 8;
    const unsigned short* gA1 = A  + (size_t)(tileM0 + m1) * D + q1 * 8;
    const unsigned short* gB0 = WT + (size_t)(tileN0 + m0) * D + q0 * 8;
    const unsigned short* gB1 = WT + (size_t)(tileN0 + m1) * D + q1 * 8;
    unsigned short* lA0 = lA + r0 * 32;
    unsigned short* lA1 = lA + (r0 + 16) * 32;
    unsigned short* lB0 = lB + r0 * 32;
    unsigned short* lB1 = lB + (r0 + 16) * 32;

    floatx4 acc[4][4] = {};

    const int quad = lane >> 4, half = lane & 15;
    int offA[4], offB[4];
#pragma unroll
    for (int i = 0; i < 4; i++) {
        int m = wr * 64 + i * 16 + half;
        offA[i] = m * 32 + ((quad + (m >> 1)) & 3) * 8;
        int n = wc * 64 + i * 16 + half;
        offB[i] = n * 32 + ((quad + (n >> 1)) & 3) * 8;
    }

    for (int k0 = 0; k0 < D; k0 += 32) {
        __syncthreads();
        __builtin_amdgcn_global_load_lds((gas_u32p)(gA0 + k0), (las_u32p)lA0, 16, 0, 0);
        __builtin_amdgcn_global_load_lds((gas_u32p)(gA1 + k0), (las_u32p)lA1, 16, 0, 0);
        __builtin_amdgcn_global_load_lds((gas_u32p)(gB0 + k0), (las_u32p)lB0, 16, 0, 0);
        __builtin_amdgcn_global_load_lds((gas_u32p)(gB1 + k0), (las_u32p)lB1, 16, 0, 0);
        __syncthreads();

        bf16x8 af[4], bfr[4];
#pragma unroll
        for (int i = 0; i < 4; i++) {
            af[i]  = *(const bf16x8*)(lA + offA[i]);
            bfr[i] = *(const bf16x8*)(lB + offB[i]);
        }
#pragma unroll
        for (int i = 0; i < 4; i++)
#pragma unroll
            for (int j = 0; j < 4; j++)
                acc[i][j] = __builtin_amdgcn_mfma_f32_16x16x32_bf16(af[i], bfr[j], acc[i][j], 0, 0, 0);
    }

    // epilogue: C/D layout col = lane&15, row = quad*4 + r (row-major H)
#pragma unroll
    for (int i = 0; i < 4; i++) {
        int gm0 = tileM0 + wr * 64 + i * 16 + quad * 4;
#pragma unroll
        for (int j = 0; j < 4; j++) {
            int gn = tileN0 + wc * 64 + j * 16 + half;
#pragma unroll
            for (int r = 0; r < 4; r++) {
                H[(size_t)(gm0 + r) * D + gn] = f2bf(acc[i][j][r]);
            }
        }
    }
}

// ---- out[row] = relu( sum_e vals[e] * h[cols[e]] ), one wave per node.
// R3-proven structure; node_base splits the work into two dispatches so
// other kernels become visible in the top-5 profile.
__global__ __launch_bounds__(256) void k_scatter_half(const int* __restrict__ rp,
                                                      const int* __restrict__ cols,
                                                      const float* __restrict__ vals,
                                                      const unsigned short* __restrict__ H,
                                                      float* __restrict__ out,
                                                      int node_base) {
    int node = node_base + (int)((blockIdx.x * 256 + threadIdx.x) >> 6);
    int lane = threadIdx.x & 63;
    if (node >= N_NODES) return;
    int s = rp[node], e = rp[node + 1];
    float a0 = 0.f, a1 = 0.f, a2 = 0.f, a3 = 0.f;
    float a4 = 0.f, a5 = 0.f, a6 = 0.f, a7 = 0.f;
    const uint4* H4 = (const uint4*)H;          // row c starts at index c*64
    const int lq = lane;                        // uint4 slot within row
    for (int t = s; t < e; t += 4) {
        int last = e - 1;
        int t1 = t + 1 < e ? t + 1 : last;
        int t2 = t + 2 < e ? t + 2 : last;
        int t3 = t + 3 < e ? t + 3 : last;
        int c0 = cols[t],  c1 = cols[t1], c2 = cols[t2], c3 = cols[t3];
        float v0 = vals[t];
        float v1 = t + 1 < e ? vals[t1] : 0.f;
        float v2 = t + 2 < e ? vals[t2] : 0.f;
        float v3 = t + 3 < e ? vals[t3] : 0.f;
        uint4 d0 = H4[(size_t)c0 * 64 + lq];
        uint4 d1 = H4[(size_t)c1 * 64 + lq];
        uint4 d2 = H4[(size_t)c2 * 64 + lq];
        uint4 d3 = H4[(size_t)c3 * 64 + lq];
        a0 = fmaf(v0, bflo(d0.x), a0); a1 = fmaf(v0, bfhi(d0.x), a1);
        a2 = fmaf(v0, bflo(d0.y), a2); a3 = fmaf(v0, bfhi(d0.y), a3);
        a4 = fmaf(v0, bflo(d0.z), a4); a5 = fmaf(v0, bfhi(d0.z), a5);
        a6 = fmaf(v0, bflo(d0.w), a6); a7 = fmaf(v0, bfhi(d0.w), a7);
        a0 = fmaf(v1, bflo(d1.x), a0); a1 = fmaf(v1, bfhi(d1.x), a1);
        a2 = fmaf(v1, bflo(d1.y), a2); a3 = fmaf(v1, bfhi(d1.y), a3);
        a4 = fmaf(v1, bflo(d1.z), a4); a5 = fmaf(v1, bfhi(d1.z), a5);
        a6 = fmaf(v1, bflo(d1.w), a6); a7 = fmaf(v1, bfhi(d1.w), a7);
        a0 = fmaf(v2, bflo(d2.x), a0); a1 = fmaf(v2, bfhi(d2.x), a1);
        a2 = fmaf(v2, bflo(d2.y), a2); a3 = fmaf(v2, bfhi(d2.y), a3);
        a4 = fmaf(v2, bflo(d2.z), a4); a5 = fmaf(v2, bfhi(d2.z), a5);
        a6 = fmaf(v2, bflo(d2.w), a6); a7 = fmaf(v2, bfhi(d2.w), a7);
        a0 = fmaf(v3, bflo(d3.x), a0); a1 = fmaf(v3, bfhi(d3.x), a1);
        a2 = fmaf(v3, bflo(d3.y), a2); a3 = fmaf(v3, bfhi(d3.y), a3);
        a4 = fmaf(v3, bflo(d3.z), a4); a5 = fmaf(v3, bfhi(d3.z), a5);
        a6 = fmaf(v3, bflo(d3.w), a6); a7 = fmaf(v3, bfhi(d3.w), a7);
    }
    float* o = out + (size_t)node * D + (size_t)lane * 8;
    *(float4*)o       = make_float4(fmaxf(a0, 0.f), fmaxf(a1, 0.f), fmaxf(a2, 0.f), fmaxf(a3, 0.f));
    *(float4*)(o + 4) = make_float4(fmaxf(a4, 0.f), fmaxf(a5, 0.f), fmaxf(a6, 0.f), fmaxf(a7, 0.f));
}

extern "C" void kernel_launch(void* const* d_in, const int* in_sizes, int n_in,
                              void* d_out, int out_size, void* d_ws, size_t ws_size,
                              hipStream_t stream) {
    const int*   adj_rows = (const int*)d_in[0];
    const int*   adj_cols = (const int*)d_in[1];
    const float* adj_vals = (const float*)d_in[2];
    const float* u_f      = (const float*)d_in[3];
    const float* weight   = (const float*)d_in[4];
    float* out = (float*)d_out;

    char* ws = (char*)d_ws;
    unsigned short* wt_bf = (unsigned short*)ws;                       // 524,288 B
    unsigned short* h_bf  = (unsigned short*)(ws + 524288);            // 51,249,152 B
    int* rowptr           = (int*)(ws + 524288 + 51249152);            // 200,004 B

    // park bf16 copy of U in d_out (consumed by GEMM before scatter overwrites)
    unsigned short* u_bf = (unsigned short*)d_out;

    hipLaunchKernelGGL(k_convert_u,  dim3(12512), dim3(256), 0, stream, u_f, u_bf);
    hipLaunchKernelGGL(k_convert_wt, dim3(1024),  dim3(256), 0, stream, weight, wt_bf);
    hipLaunchKernelGGL(k_rowptr,     dim3(196),   dim3(256), 0, stream, adj_rows, rowptr);
    hipLaunchKernelGGL(k_gemm,       dim3(1564),  dim3(256), 0, stream, u_bf, wt_bf, h_bf);
    hipLaunchKernelGGL(k_scatter_half, dim3(6250), dim3(256), 0, stream, rowptr, adj_cols, adj_vals, h_bf, out, 0);
    hipLaunchKernelGGL(k_scatter_half, dim3(6250), dim3(256), 0, stream, rowptr, adj_cols, adj_vals, h_bf, out, 25000);
}